// Round 1
// baseline (526.241 us; speedup 1.0000x reference)
//
#include <hip/hip_runtime.h>

typedef _Float16 half2_t __attribute__((ext_vector_type(2)));
typedef unsigned int uint;

#define D 128
#define O 64
#define UNR 8

static inline size_t align_up(size_t x, size_t a) { return (x + a - 1) & ~(a - 1); }

__device__ __forceinline__ uint pack_f16(float a, float b) {
  half2_t h;
  h.x = (_Float16)a;
  h.y = (_Float16)b;
  return *(uint*)&h;
}

__device__ __forceinline__ float dot2f(uint a, uint b, float c) {
#if defined(__has_builtin) && __has_builtin(__builtin_amdgcn_fdot2)
  return __builtin_amdgcn_fdot2(*(half2_t*)&a, *(half2_t*)&b, c, false);
#else
  half2_t ha = *(half2_t*)&a, hb = *(half2_t*)&b;
  return c + (float)ha.x * (float)hb.x + (float)ha.y * (float)hb.y;
#endif
}

// ---------------- setup kernels ----------------
// deg = in-edge count (no self loop; memset to 0 before). dinv = rsqrt(deg+1).

__global__ void count_deg_k(const int* __restrict__ col, int* __restrict__ deg, int E, int n) {
  int i = blockIdx.x * blockDim.x + threadIdx.x;
  if (i >= E) return;
  int c = col[i];
  if ((unsigned)c >= (unsigned)n) return;
  atomicAdd(&deg[c], 1);
}

__global__ void scan1_k(const int* __restrict__ deg, int* __restrict__ row_ptr,
                        int* __restrict__ bsum, float* __restrict__ dinv, int n) {
  __shared__ int s[256];
  int tid = threadIdx.x;
  int gid = blockIdx.x * 256 + tid;
  int dg = (gid < n) ? deg[gid] : 0;
  if (gid < n) dinv[gid] = rsqrtf((float)(dg + 1));
  s[tid] = dg;
  __syncthreads();
  for (int off = 1; off < 256; off <<= 1) {
    int t = (tid >= off) ? s[tid - off] : 0;
    __syncthreads();
    s[tid] += t;
    __syncthreads();
  }
  if (gid < n) row_ptr[gid] = s[tid] - dg;  // block-local exclusive
  if (tid == 255) bsum[blockIdx.x] = s[255];
}

__global__ void scan2_k(int* __restrict__ bsum, int nb) {
  __shared__ int s[512];
  int tid = threadIdx.x;
  int v = (tid < nb) ? bsum[tid] : 0;
  s[tid] = v;
  __syncthreads();
  for (int off = 1; off < 512; off <<= 1) {
    int t = (tid >= off) ? s[tid - off] : 0;
    __syncthreads();
    s[tid] += t;
    __syncthreads();
  }
  if (tid < nb) bsum[tid] = s[tid] - v;
}

__global__ void scan3_k(const int* __restrict__ bsum, const int* __restrict__ deg,
                        int* __restrict__ row_ptr, int* __restrict__ cursor, int n) {
  int gid = blockIdx.x * 256 + threadIdx.x;
  if (gid < n) {
    int r = row_ptr[gid] + bsum[blockIdx.x];
    row_ptr[gid] = r;
    cursor[gid] = r;
    if (gid == n - 1) row_ptr[n] = r + deg[gid];
  }
}

__global__ void fill_k(const int* __restrict__ rows, const int* __restrict__ cols,
                       int* __restrict__ cursor, const float* __restrict__ dinv,
                       int2* __restrict__ csr, int E, int n) {
  int i = blockIdx.x * blockDim.x + threadIdx.x;
  if (i >= E) return;
  int u = rows[i], v = cols[i];
  if ((unsigned)v >= (unsigned)n) return;  // must match count_deg_k skip
  if ((unsigned)u >= (unsigned)n) u = 0;
  int slot = atomicAdd(&cursor[v], 1);
  float nrm = dinv[u] * dinv[v];
  csr[slot] = make_int2(u, __float_as_int(nrm));
}

// softmax over hop weights + pack W to f16x2, TRANSPOSED: Wpk[dd*64+o]
__global__ void prep_k(const float* __restrict__ t, float* __restrict__ tn,
                       const float* __restrict__ W, uint* __restrict__ Wpk, int step) {
  int tid = threadIdx.x;
  if (tid < D) {
    float vals[16];
    float m = -1e30f;
    for (int k = 0; k < step; ++k) { vals[k] = t[k * D + tid]; m = fmaxf(m, vals[k]); }
    float ssum = 0.f;
    for (int k = 0; k < step; ++k) { vals[k] = expf(vals[k] - m); ssum += vals[k]; }
    float inv = 1.f / ssum;
    for (int k = 0; k < step; ++k) tn[k * D + tid] = vals[k] * inv;
  }
  for (int i = tid; i < O * 64; i += 256) {
    int o = i & 63, dd = i >> 6;  // i = dd*64 + o
    Wpk[i] = pack_f16(W[o * D + 2 * dd], W[o * D + 2 * dd + 1]);
  }
}

__global__ void init_h_k(const float* __restrict__ x, uint* __restrict__ h0, int total) {
  int i = blockIdx.x * blockDim.x + threadIdx.x;
  if (i >= total) return;
  float2 v = ((const float2*)x)[i];
  h0[i] = pack_f16(v.x, v.y);
}

// ---------------- fused hop: h_new = A_norm*h_old, paired y accumulation ------
// DO_Y: 0 = none
//       1 = y  = tprev*h_old + tcur*h_new      (first pair, write-only)
//       2 = y += tprev*h_old + tcur*h_new      (RMW pair)
//       3 = y += tcur*h_new                     (odd-step tail, RMW single)
// Both h_old and h_new terms are already in registers -> y costs only the
// f16 y-row stream (read+write 25.6 MB) on the odd hops, nothing else.

template <int DO_Y>
__global__ __launch_bounds__(256) void hop_f_k(
    const uint* __restrict__ h_old, uint* __restrict__ h_new, uint* __restrict__ y,
    const int* __restrict__ row_ptr, const int2* __restrict__ csr,
    const float* __restrict__ dinv, const float* __restrict__ tprev,
    const float* __restrict__ tcur, int n) {
  int wid = (blockIdx.x * blockDim.x + threadIdx.x) >> 6;
  int lane = threadIdx.x & 63;
  if (wid >= n) return;
  int v = __builtin_amdgcn_readfirstlane(wid);
  float dv = dinv[v];
  float ns = dv * dv;  // self-loop norm
  uint hp = h_old[(size_t)v * 64 + lane];
  half2_t hv = *(half2_t*)&hp;
  float hx = (float)hv.x, hy = (float)hv.y;
  float ax = ns * hx, ay = ns * hy;
  int beg = __builtin_amdgcn_readfirstlane(row_ptr[v]);
  int end = __builtin_amdgcn_readfirstlane(row_ptr[v + 1]);
  for (int i = beg; i < end; i += UNR) {
    int u[UNR];
    float w[UNR];
#pragma unroll
    for (int j = 0; j < UNR; ++j) {
      int ic = i + j;
      int icl = (ic < end - 1) ? ic : (end - 1);
      int2 e = csr[icl];
      u[j] = e.x;
      w[j] = (ic < end) ? __int_as_float(e.y) : 0.f;
    }
    uint g[UNR];
#pragma unroll
    for (int j = 0; j < UNR; ++j) g[j] = h_old[(size_t)u[j] * 64 + lane];
#pragma unroll
    for (int j = 0; j < UNR; ++j) {
      half2_t h = *(half2_t*)&g[j];
      ax += w[j] * (float)h.x;
      ay += w[j] * (float)h.y;
    }
  }
  h_new[(size_t)v * 64 + lane] = pack_f16(ax, ay);
  if (DO_Y) {
    float yx = 0.f, yy = 0.f;
    if (DO_Y != 3) {
      float2 ta = ((const float2*)tprev)[lane];
      yx = ta.x * hx;
      yy = ta.y * hy;
    }
    float2 tb = ((const float2*)tcur)[lane];
    yx += tb.x * ax;
    yy += tb.y * ay;
    if (DO_Y >= 2) {
      uint yo = y[(size_t)v * 64 + lane];
      half2_t yh = *(half2_t*)&yo;
      yx += (float)yh.x;
      yy += (float)yh.y;
    }
    y[(size_t)v * 64 + lane] = pack_f16(yx, yy);
  }
}

// ---------------- proj from fused y: out = y @ W^T + b ----------------
// Coalesced y-row load -> wave-local LDS broadcast -> b128 reads + v_dot2.
// Chunked node ownership: each wave owns PNW contiguous nodes.

#define PNW 8

__global__ __launch_bounds__(256) void proj_y2_k(
    const uint* __restrict__ y, const uint* __restrict__ Wpk,
    const float* __restrict__ b, float* __restrict__ out, int n) {
  __shared__ uint sy[4][64];
  int tid = threadIdx.x;
  int lane = tid & 63, wv = tid >> 6;
  uint wreg[64];
#pragma unroll
  for (int j = 0; j < 64; ++j) wreg[j] = Wpk[j * 64 + lane];  // coalesced (transposed)
  float bias = b[lane];
  int wid = (blockIdx.x * blockDim.x + tid) >> 6;
  int vb = wid * PNW;
  int ve = vb + PNW < n ? vb + PNW : n;
  for (int v = vb; v < ve; ++v) {
    sy[wv][lane] = y[(size_t)v * 64 + lane];  // wave-local broadcast buffer
    float acc = bias;
#pragma unroll
    for (int q = 0; q < 16; ++q) {
      uint4 yq = *(const uint4*)&sy[wv][q * 4];  // broadcast b128 read
      acc = dot2f(yq.x, wreg[q * 4 + 0], acc);
      acc = dot2f(yq.y, wreg[q * 4 + 1], acc);
      acc = dot2f(yq.z, wreg[q * 4 + 2], acc);
      acc = dot2f(yq.w, wreg[q * 4 + 3], acc);
    }
    out[(size_t)v * O + lane] = acc;
  }
}

// ---------------- launch ----------------

extern "C" void kernel_launch(void* const* d_in, const int* in_sizes, int n_in,
                              void* d_out, int out_size, void* d_ws, size_t ws_size,
                              hipStream_t stream) {
  const float* x = (const float*)d_in[0];
  const int* ei = (const int*)d_in[1];
  const float* t = (const float*)d_in[2];
  const float* W = (const float*)d_in[3];
  const float* b = (const float*)d_in[4];
  float* out = (float*)d_out;

  int n = in_sizes[0] / D;
  int E = in_sizes[1] / 2;
  int step = in_sizes[2] / D;  // = 10
  const int* rows = ei;        // sources
  const int* cols = ei + E;    // targets

  char* p = (char*)d_ws;
  auto alloc = [&](size_t bytes) { char* r = p; p += align_up(bytes, 256); return r; };
  int*   deg     = (int*)alloc((size_t)n * 4);
  float* dinv    = (float*)alloc((size_t)n * 4);
  int*   row_ptr = (int*)alloc((size_t)(n + 1) * 4);
  int*   cursor  = (int*)alloc((size_t)n * 4);
  int*   bsum    = (int*)alloc(2048);
  int2*  csr     = (int2*)alloc((size_t)E * 8);
  float* tn      = (float*)alloc((size_t)step * D * 4);
  uint*  Wpk     = (uint*)alloc((size_t)O * 64 * 4);

  size_t NS = (size_t)n * 64;  // uints per h buffer
  uint* h_a  = (uint*)alloc(NS * 4);
  uint* h_b  = (uint*)alloc(NS * 4);
  uint* ybuf = (uint*)alloc(NS * 4);

  // ---- setup ----
  hipMemsetAsync(deg, 0, (size_t)n * 4, stream);
  int nb1 = (n + 255) / 256;
  count_deg_k<<<(E + 255) / 256, 256, 0, stream>>>(cols, deg, E, n);
  scan1_k<<<nb1, 256, 0, stream>>>(deg, row_ptr, bsum, dinv, n);
  scan2_k<<<1, 512, 0, stream>>>(bsum, nb1);
  scan3_k<<<nb1, 256, 0, stream>>>(bsum, deg, row_ptr, cursor, n);
  fill_k<<<(E + 255) / 256, 256, 0, stream>>>(rows, cols, cursor, dinv, csr, E, n);
  prep_k<<<1, 256, 0, stream>>>(t, tn, W, Wpk, step);

  int hop_blocks = (n + 3) / 4;  // 1 node/wave, 4 waves/block
  int proj_blocks = (n + PNW * 4 - 1) / (PNW * 4);

  // ---- fused hops (ping-pong h, in-hop paired y accumulation) ----
  init_h_k<<<((size_t)NS + 255) / 256, 256, 0, stream>>>(x, h_a, (int)NS);
  uint* ho = h_a;
  uint* hn = h_b;
  for (int k = 1; k < step; ++k) {
    const float* tp = tn + (size_t)(k - 1) * D;
    const float* tc = tn + (size_t)k * D;
    if (k & 1) {
      if (k == 1)
        hop_f_k<1><<<hop_blocks, 256, 0, stream>>>(ho, hn, ybuf, row_ptr, csr, dinv, tp, tc, n);
      else
        hop_f_k<2><<<hop_blocks, 256, 0, stream>>>(ho, hn, ybuf, row_ptr, csr, dinv, tp, tc, n);
    } else if (k == step - 1) {
      // only reached when step is odd: tail single-term accumulation
      hop_f_k<3><<<hop_blocks, 256, 0, stream>>>(ho, hn, ybuf, row_ptr, csr, dinv, tp, tc, n);
    } else {
      hop_f_k<0><<<hop_blocks, 256, 0, stream>>>(ho, hn, ybuf, row_ptr, csr, dinv, tp, tc, n);
    }
    uint* tmp = ho; ho = hn; hn = tmp;
  }

  proj_y2_k<<<proj_blocks, 256, 0, stream>>>(ybuf, Wpk, b, out, n);
}

// Round 2
// 525.744 us; speedup vs baseline: 1.0009x; 1.0009x over previous
//
#include <hip/hip_runtime.h>

typedef _Float16 half2_t __attribute__((ext_vector_type(2)));
typedef unsigned int uint;

#define D 128
#define O 64
#define UNR 8
#define NPW 8   // nodes per wave in hop
#define PNW 8   // nodes per wave in proj

static inline size_t align_up(size_t x, size_t a) { return (x + a - 1) & ~(a - 1); }

__device__ __forceinline__ uint pack_f16(float a, float b) {
  half2_t h;
  h.x = (_Float16)a;
  h.y = (_Float16)b;
  return *(uint*)&h;
}

__device__ __forceinline__ float dot2f(uint a, uint b, float c) {
#if defined(__has_builtin) && __has_builtin(__builtin_amdgcn_fdot2)
  return __builtin_amdgcn_fdot2(*(half2_t*)&a, *(half2_t*)&b, c, false);
#else
  half2_t ha = *(half2_t*)&a, hb = *(half2_t*)&b;
  return c + (float)ha.x * (float)hb.x + (float)ha.y * (float)hb.y;
#endif
}

// ---------------- setup kernels ----------------

__global__ void count_deg_k(const int* __restrict__ col, int* __restrict__ deg, int E, int n) {
  int i = blockIdx.x * blockDim.x + threadIdx.x;
  if (i >= E) return;
  int c = col[i];
  if ((unsigned)c >= (unsigned)n) return;
  atomicAdd(&deg[c], 1);
}

__global__ void scan1_k(const int* __restrict__ deg, int* __restrict__ row_ptr,
                        int* __restrict__ bsum, float* __restrict__ dinv, int n) {
  __shared__ int s[256];
  int tid = threadIdx.x;
  int gid = blockIdx.x * 256 + tid;
  int dg = (gid < n) ? deg[gid] : 0;
  if (gid < n) dinv[gid] = rsqrtf((float)(dg + 1));
  s[tid] = dg;
  __syncthreads();
  for (int off = 1; off < 256; off <<= 1) {
    int t = (tid >= off) ? s[tid - off] : 0;
    __syncthreads();
    s[tid] += t;
    __syncthreads();
  }
  if (gid < n) row_ptr[gid] = s[tid] - dg;  // block-local exclusive
  if (tid == 255) bsum[blockIdx.x] = s[255];
}

__global__ void scan2_k(int* __restrict__ bsum, int nb) {
  __shared__ int s[512];
  int tid = threadIdx.x;
  int v = (tid < nb) ? bsum[tid] : 0;
  s[tid] = v;
  __syncthreads();
  for (int off = 1; off < 512; off <<= 1) {
    int t = (tid >= off) ? s[tid - off] : 0;
    __syncthreads();
    s[tid] += t;
    __syncthreads();
  }
  if (tid < nb) bsum[tid] = s[tid] - v;
}

__global__ void scan3_k(const int* __restrict__ bsum, const int* __restrict__ deg,
                        int* __restrict__ row_ptr, int* __restrict__ cursor, int n) {
  int gid = blockIdx.x * 256 + threadIdx.x;
  if (gid < n) {
    int r = row_ptr[gid] + bsum[blockIdx.x];
    row_ptr[gid] = r;
    cursor[gid] = r;
    if (gid == n - 1) row_ptr[n] = r + deg[gid];
  }
}

__global__ void fill_k(const int* __restrict__ rows, const int* __restrict__ cols,
                       int* __restrict__ cursor, const float* __restrict__ dinv,
                       int2* __restrict__ csr, int E, int n) {
  int i = blockIdx.x * blockDim.x + threadIdx.x;
  if (i >= E) return;
  int u = rows[i], v = cols[i];
  if ((unsigned)v >= (unsigned)n) return;  // must match count_deg_k skip
  if ((unsigned)u >= (unsigned)n) u = 0;
  int slot = atomicAdd(&cursor[v], 1);
  float nrm = dinv[u] * dinv[v];
  csr[slot] = make_int2(u, __float_as_int(nrm));
}

// softmax over hop weights + pack W to f16x2, TRANSPOSED: Wpk[dd*64+o]
__global__ void prep_k(const float* __restrict__ t, float* __restrict__ tn,
                       const float* __restrict__ W, uint* __restrict__ Wpk, int step) {
  int tid = threadIdx.x;
  if (tid < D) {
    float vals[16];
    float m = -1e30f;
    for (int k = 0; k < step; ++k) { vals[k] = t[k * D + tid]; m = fmaxf(m, vals[k]); }
    float ssum = 0.f;
    for (int k = 0; k < step; ++k) { vals[k] = expf(vals[k] - m); ssum += vals[k]; }
    float inv = 1.f / ssum;
    for (int k = 0; k < step; ++k) tn[k * D + tid] = vals[k] * inv;
  }
  for (int i = tid; i < O * 64; i += 256) {
    int o = i & 63, dd = i >> 6;  // i = dd*64 + o
    Wpk[i] = pack_f16(W[o * D + 2 * dd], W[o * D + 2 * dd + 1]);
  }
}

__global__ void init_h_k(const float* __restrict__ x, uint* __restrict__ h0, int total) {
  int i = blockIdx.x * blockDim.x + threadIdx.x;
  if (i >= total) return;
  float2 v = ((const float2*)x)[i];
  h0[i] = pack_f16(v.x, v.y);
}

// ---------------- multi-node pipelined hop ----------------
// Each wave owns NPW contiguous nodes => one contiguous CSR edge range.
// Edge stream is processed in UNR batches with next-batch csr prefetch;
// per-node state (h_old row, dinv, old y) is prefetched 1 node ahead in
// rotating registers. All bookkeeping is wave-uniform (scalar pipe).
// DO_Y: 0 none | 1 y = tp*h_old + tc*h_new | 2 y += pair | 3 y += tc*h_new

template <int DO_Y>
__global__ __launch_bounds__(256) void hop_m_k(
    const uint* __restrict__ hsrc, uint* __restrict__ hdst, uint* __restrict__ y,
    const int* __restrict__ row_ptr, const int2* __restrict__ csr,
    const float* __restrict__ dinv, const float* __restrict__ tprev,
    const float* __restrict__ tcur, int n) {
  int wid = (blockIdx.x * blockDim.x + threadIdx.x) >> 6;
  int lane = threadIdx.x & 63;
  int v0 = wid * NPW;
  if (v0 >= n) return;
  int vN = (v0 + NPW < n) ? v0 + NPW : n;

  float2 ta = make_float2(0.f, 0.f), tb = make_float2(0.f, 0.f);
  if (DO_Y) {
    if (DO_Y != 3) ta = ((const float2*)tprev)[lane];
    tb = ((const float2*)tcur)[lane];
  }

  // rotating per-node state: current + one prefetched ahead
  int vcur = v0;
  uint hc = hsrc[(v0 << 6) + lane];
  float dvc = dinv[v0];
  uint yc = 0, yn = 0;
  if (DO_Y >= 2) yc = y[(v0 << 6) + lane];
  int v1c = (v0 + 1 < vN) ? v0 + 1 : vN - 1;
  uint hn = hsrc[(v1c << 6) + lane];
  float dvn = dinv[v1c];
  if (DO_Y >= 2) yn = y[(v1c << 6) + lane];

  int eBeg = __builtin_amdgcn_readfirstlane(row_ptr[v0]);
  int eEnd = __builtin_amdgcn_readfirstlane(row_ptr[vN]);
  int nend = __builtin_amdgcn_readfirstlane(row_ptr[v0 + 1]);
  int v2c = (v0 + 2 <= n) ? v0 + 2 : n;
  int nefly = row_ptr[v2c];  // in-flight row_ptr[vcur+2]

  float hcx, hcy;
  { half2_t h = *(half2_t*)&hc; hcx = (float)h.x; hcy = (float)h.y; }
  float accx = 0.f, accy = 0.f;

#define FLUSH()                                                              \
  {                                                                          \
    float ns = dvc * dvc;                                                    \
    float fx = accx + ns * hcx, fy = accy + ns * hcy;                        \
    hdst[(vcur << 6) + lane] = pack_f16(fx, fy);                             \
    if (DO_Y) {                                                              \
      float yx, yy;                                                          \
      if (DO_Y == 3) {                                                       \
        yx = tb.x * fx; yy = tb.y * fy;                                      \
      } else {                                                               \
        yx = ta.x * hcx + tb.x * fx;                                         \
        yy = ta.y * hcy + tb.y * fy;                                         \
      }                                                                      \
      if (DO_Y >= 2) {                                                       \
        half2_t yh = *(half2_t*)&yc;                                         \
        yx += (float)yh.x; yy += (float)yh.y;                                \
      }                                                                      \
      y[(vcur << 6) + lane] = pack_f16(yx, yy);                              \
    }                                                                        \
    accx = 0.f; accy = 0.f;                                                  \
    vcur++;                                                                  \
    hc = hn; dvc = dvn;                                                      \
    if (DO_Y >= 2) yc = yn;                                                  \
    { half2_t h = *(half2_t*)&hc; hcx = (float)h.x; hcy = (float)h.y; }      \
    int vp = (vcur + 1 < vN) ? vcur + 1 : vN - 1;                            \
    hn = hsrc[(vp << 6) + lane];                                             \
    dvn = dinv[vp];                                                          \
    if (DO_Y >= 2) yn = y[(vp << 6) + lane];                                 \
    nend = __builtin_amdgcn_readfirstlane(nefly);                            \
    int v2 = (vcur + 2 <= n) ? vcur + 2 : n;                                 \
    nefly = row_ptr[v2];                                                     \
  }

  // prime first csr batch (wave-uniform indices -> scalar loads)
  int2 eb[UNR];
  if (eBeg < eEnd) {
#pragma unroll
    for (int j = 0; j < UNR; ++j) {
      int ic = eBeg + j;
      if (ic > eEnd - 1) ic = eEnd - 1;
      eb[j] = csr[ic];
    }
  }

  for (int e = eBeg; e < eEnd; e += UNR) {
    // issue gathers for current batch
    uint g[UNR];
#pragma unroll
    for (int j = 0; j < UNR; ++j) g[j] = hsrc[(eb[j].x << 6) + lane];
    float w[UNR];
#pragma unroll
    for (int j = 0; j < UNR; ++j) w[j] = __int_as_float(eb[j].y);
    // prefetch next batch's csr (independent of gathers)
    int2 nb[UNR];
#pragma unroll
    for (int j = 0; j < UNR; ++j) {
      int ic = e + UNR + j;
      if (ic > eEnd - 1) ic = eEnd - 1;
      nb[j] = csr[ic];
    }
    // accumulate with uniform segmented flush
#pragma unroll
    for (int j = 0; j < UNR; ++j) {
      int eid = e + j;
      if (eid < eEnd) {
        while (vcur < vN - 1 && nend == eid) { FLUSH(); }
        half2_t h = *(half2_t*)&g[j];
        accx += w[j] * (float)h.x;
        accy += w[j] * (float)h.y;
      }
    }
#pragma unroll
    for (int j = 0; j < UNR; ++j) eb[j] = nb[j];
  }
  // trailing flushes (nodes ending at eEnd, incl. empty nodes)
  while (vcur < vN) { FLUSH(); }
#undef FLUSH
}

// ---------------- proj from fused y: out = y @ W^T + b ----------------

__global__ __launch_bounds__(256) void proj_y2_k(
    const uint* __restrict__ y, const uint* __restrict__ Wpk,
    const float* __restrict__ b, float* __restrict__ out, int n) {
  __shared__ uint sy[4][64];
  int tid = threadIdx.x;
  int lane = tid & 63, wv = tid >> 6;
  uint wreg[64];
#pragma unroll
  for (int j = 0; j < 64; ++j) wreg[j] = Wpk[j * 64 + lane];  // coalesced (transposed)
  float bias = b[lane];
  int wid = (blockIdx.x * blockDim.x + tid) >> 6;
  int vb = wid * PNW;
  int ve = vb + PNW < n ? vb + PNW : n;
  for (int v = vb; v < ve; ++v) {
    sy[wv][lane] = y[(size_t)v * 64 + lane];  // wave-local broadcast buffer
    float acc = bias;
#pragma unroll
    for (int q = 0; q < 16; ++q) {
      uint4 yq = *(const uint4*)&sy[wv][q * 4];  // broadcast b128 read
      acc = dot2f(yq.x, wreg[q * 4 + 0], acc);
      acc = dot2f(yq.y, wreg[q * 4 + 1], acc);
      acc = dot2f(yq.z, wreg[q * 4 + 2], acc);
      acc = dot2f(yq.w, wreg[q * 4 + 3], acc);
    }
    out[(size_t)v * O + lane] = acc;
  }
}

// ---------------- launch ----------------

extern "C" void kernel_launch(void* const* d_in, const int* in_sizes, int n_in,
                              void* d_out, int out_size, void* d_ws, size_t ws_size,
                              hipStream_t stream) {
  const float* x = (const float*)d_in[0];
  const int* ei = (const int*)d_in[1];
  const float* t = (const float*)d_in[2];
  const float* W = (const float*)d_in[3];
  const float* b = (const float*)d_in[4];
  float* out = (float*)d_out;

  int n = in_sizes[0] / D;
  int E = in_sizes[1] / 2;
  int step = in_sizes[2] / D;  // = 10
  const int* rows = ei;        // sources
  const int* cols = ei + E;    // targets

  char* p = (char*)d_ws;
  auto alloc = [&](size_t bytes) { char* r = p; p += align_up(bytes, 256); return r; };
  int*   deg     = (int*)alloc((size_t)n * 4);
  float* dinv    = (float*)alloc((size_t)n * 4);
  int*   row_ptr = (int*)alloc((size_t)(n + 1) * 4);
  int*   cursor  = (int*)alloc((size_t)n * 4);
  int*   bsum    = (int*)alloc(2048);
  int2*  csr     = (int2*)alloc((size_t)E * 8);
  float* tn      = (float*)alloc((size_t)step * D * 4);
  uint*  Wpk     = (uint*)alloc((size_t)O * 64 * 4);

  size_t NS = (size_t)n * 64;  // uints per h buffer
  uint* h_a  = (uint*)alloc(NS * 4);
  uint* h_b  = (uint*)alloc(NS * 4);
  uint* ybuf = (uint*)alloc(NS * 4);

  // ---- setup ----
  hipMemsetAsync(deg, 0, (size_t)n * 4, stream);
  int nb1 = (n + 255) / 256;
  count_deg_k<<<(E + 255) / 256, 256, 0, stream>>>(cols, deg, E, n);
  scan1_k<<<nb1, 256, 0, stream>>>(deg, row_ptr, bsum, dinv, n);
  scan2_k<<<1, 512, 0, stream>>>(bsum, nb1);
  scan3_k<<<nb1, 256, 0, stream>>>(bsum, deg, row_ptr, cursor, n);
  fill_k<<<(E + 255) / 256, 256, 0, stream>>>(rows, cols, cursor, dinv, csr, E, n);
  prep_k<<<1, 256, 0, stream>>>(t, tn, W, Wpk, step);

  int hop_blocks = (n + NPW * 4 - 1) / (NPW * 4);  // NPW nodes/wave, 4 waves/block
  int proj_blocks = (n + PNW * 4 - 1) / (PNW * 4);

  // ---- fused hops (ping-pong h, in-hop paired y accumulation) ----
  init_h_k<<<((size_t)NS + 255) / 256, 256, 0, stream>>>(x, h_a, (int)NS);
  uint* ho = h_a;
  uint* hn = h_b;
  for (int k = 1; k < step; ++k) {
    const float* tp = tn + (size_t)(k - 1) * D;
    const float* tc = tn + (size_t)k * D;
    if (k & 1) {
      if (k == 1)
        hop_m_k<1><<<hop_blocks, 256, 0, stream>>>(ho, hn, ybuf, row_ptr, csr, dinv, tp, tc, n);
      else
        hop_m_k<2><<<hop_blocks, 256, 0, stream>>>(ho, hn, ybuf, row_ptr, csr, dinv, tp, tc, n);
    } else if (k == step - 1) {
      // only reached when step is odd: tail single-term accumulation
      hop_m_k<3><<<hop_blocks, 256, 0, stream>>>(ho, hn, ybuf, row_ptr, csr, dinv, tp, tc, n);
    } else {
      hop_m_k<0><<<hop_blocks, 256, 0, stream>>>(ho, hn, ybuf, row_ptr, csr, dinv, tp, tc, n);
    }
    uint* tmp = ho; ho = hn; hn = tmp;
  }

  proj_y2_k<<<proj_blocks, 256, 0, stream>>>(ybuf, Wpk, b, out, n);
}